// Round 11
// baseline (113.729 us; speedup 1.0000x reference)
//
#include <hip/hip_runtime.h>

#define S_LEN 2048
#define HID   1280
#define NH    16
#define HD    80
#define WIN   64
#define NWIN  (S_LEN / WIN)

typedef _Float16 half4v __attribute__((ext_vector_type(4)));
typedef _Float16 half8v __attribute__((ext_vector_type(8)));
typedef float    float4v __attribute__((ext_vector_type(4)));

__device__ __forceinline__ void gload16(const _Float16* g, _Float16* l)
{
    __builtin_amdgcn_global_load_lds((const __attribute__((address_space(1))) void*)g,
                                     (__attribute__((address_space(3))) void*)l,
                                     16, 0, 0);
}

template <int N>
__device__ __forceinline__ void waitcnt_vm()
{
    if constexpr (N == 0)      asm volatile("s_waitcnt vmcnt(0)" ::: "memory");
    else if constexpr (N == 3) asm volatile("s_waitcnt vmcnt(3)" ::: "memory");
    else static_assert(N < 0, "add literal");
}

__device__ __forceinline__ void cfence() { asm volatile("" ::: "memory"); }

// ---------------- fp32 -> fp16 conversion (hidden + qkv_w) ----------------
__global__ void cvt_two(const float* __restrict__ a, _Float16* __restrict__ oa, int na4,
                        const float* __restrict__ b, _Float16* __restrict__ ob, int nb4)
{
    int i = blockIdx.x * blockDim.x + threadIdx.x;
    const float* in; _Float16* out; int idx;
    if (i < na4)            { in = a; out = oa; idx = i; }
    else if (i < na4 + nb4) { in = b; out = ob; idx = i - na4; }
    else return;
    float4v v = ((const float4v*)in)[idx];
    half4v h;
    h[0] = (_Float16)v[0]; h[1] = (_Float16)v[1];
    h[2] = (_Float16)v[2]; h[3] = (_Float16)v[3];
    ((half4v*)out)[idx] = h;
}

// ---------------- qkv GEMM: register-direct, LDS-free, barrier-free ----------------
// C[2048][3840] = A[2048][1280] * B[3840][1280]^T + bias.
// 256 thr = 4 waves (2x2), each wave owns a 64x64 output tile and loads its
// MFMA fragments straight global->VGPR (no LDS, no barriers -> waves slip
// independently; stalls overlap via TLP across 1920 waves).
// Register double-buffer at k-chunk (32) granularity: load(c+1) || MFMA(c).
// Frag (16x16x32): lane(g,r) reads 8 halves at row(+r), col g*8 -> lanes with
// same r form 64B segments; other half-line consumed by next k-chunk (L1-hit).
__global__ __launch_bounds__(256) void gemm_qkv_reg(
    const _Float16* __restrict__ A,    // [2048][1280]
    const _Float16* __restrict__ B,    // [3840][1280]
    const float*    __restrict__ bias,
    _Float16*       __restrict__ C)    // [2048][3840]
{
    constexpr int K = HID, N = 3 * HID;
    constexpr int NC = K / 32;                 // 40 k-chunks
    const int lane = threadIdx.x & 63, wave = threadIdx.x >> 6;
    const int g = lane >> 4, r = lane & 15;
    const int row0 = blockIdx.x * 128 + (wave >> 1) * 64;
    const int col0 = blockIdx.y * 128 + (wave & 1) * 64;

    // per-fragment base pointers (k advances by +32 halves per chunk)
    const _Float16* pa[4];
    const _Float16* pb[4];
#pragma unroll
    for (int m = 0; m < 4; m++) pa[m] = A + (size_t)(row0 + m * 16 + r) * K + g * 8;
#pragma unroll
    for (int n = 0; n < 4; n++) pb[n] = B + (size_t)(col0 + n * 16 + r) * K + g * 8;

    float4v acc[4][4];
    const float4v zero = {0.f, 0.f, 0.f, 0.f};
#pragma unroll
    for (int m = 0; m < 4; m++)
#pragma unroll
        for (int n = 0; n < 4; n++) acc[m][n] = zero;

    half8v aX[4], bX[4], aY[4], bY[4];

    // prologue: chunk 0 -> X
#pragma unroll
    for (int m = 0; m < 4; m++) aX[m] = *(const half8v*)(pa[m]);
#pragma unroll
    for (int n = 0; n < 4; n++) bX[n] = *(const half8v*)(pb[n]);

    for (int c = 0; c < NC; c += 2) {
        // load Y = chunk c+1 (always exists: NC even, c <= NC-2)
#pragma unroll
        for (int m = 0; m < 4; m++) aY[m] = *(const half8v*)(pa[m] + (c + 1) * 32);
#pragma unroll
        for (int n = 0; n < 4; n++) bY[n] = *(const half8v*)(pb[n] + (c + 1) * 32);
        // MFMA on X (chunk c) — Y loads fly underneath
#pragma unroll
        for (int m = 0; m < 4; m++)
#pragma unroll
            for (int n = 0; n < 4; n++)
                acc[m][n] = __builtin_amdgcn_mfma_f32_16x16x32_f16(aX[m], bX[n], acc[m][n], 0, 0, 0);
        // load X = chunk c+2
        if (c + 2 < NC) {
#pragma unroll
            for (int m = 0; m < 4; m++) aX[m] = *(const half8v*)(pa[m] + (c + 2) * 32);
#pragma unroll
            for (int n = 0; n < 4; n++) bX[n] = *(const half8v*)(pb[n] + (c + 2) * 32);
        }
        // MFMA on Y (chunk c+1)
#pragma unroll
        for (int m = 0; m < 4; m++)
#pragma unroll
            for (int n = 0; n < 4; n++)
                acc[m][n] = __builtin_amdgcn_mfma_f32_16x16x32_f16(aY[m], bY[n], acc[m][n], 0, 0, 0);
    }

#pragma unroll
    for (int m = 0; m < 4; m++)
#pragma unroll
        for (int n = 0; n < 4; n++) {
            int col = col0 + n * 16 + r;
            float bv = bias[col];
#pragma unroll
            for (int i = 0; i < 4; i++) {
                int row = row0 + m * 16 + g * 4 + i;
                C[(size_t)row * N + col] = (_Float16)(acc[m][n][i] + bv);
            }
        }
}

// ---------------- proj GEMM (r7 verified structure) ----------------
__global__ __launch_bounds__(512) void gemm_proj(
    const _Float16* __restrict__ A,    // attn16 [2048][1280]
    const _Float16* __restrict__ B,    // projw16 [1280][1280]
    const float*    __restrict__ bias,
    float*          __restrict__ C)    // [2048][1280]
{
    constexpr int K = HID, N = HID;
    constexpr int MR = 2, NR = 2, CA = 1, CB = 2, CHUNKS = 3;
    __shared__ _Float16 As[2][64 * 64];
    __shared__ _Float16 Bs[2][128 * 64];

    const int t = threadIdx.x;
    const int lane = t & 63, wave = t >> 6;
    const int g = lane >> 4, r = lane & 15;
    const int wr = (wave >> 2) * 32, wc = (wave & 3) * 32;
    const int row_a0 = blockIdx.x * 64, row_b0 = blockIdx.y * 128;

    const int srow = lane >> 3;
    const int scol = ((lane & 7) ^ srow) * 8;

    auto stage = [&](int buf, int k0) {
#pragma unroll
        for (int i = 0; i < CA; i++) {
            int c = wave * CA + i;
            gload16(&A[(size_t)(row_a0 + c * 8 + srow) * K + k0 + scol], &As[buf][c * 512]);
        }
#pragma unroll
        for (int i = 0; i < CB; i++) {
            int c = wave * CB + i;
            gload16(&B[(size_t)(row_b0 + c * 8 + srow) * K + k0 + scol], &Bs[buf][c * 512]);
        }
    };

    float4v acc[MR][NR];
    const float4v zero = {0.f, 0.f, 0.f, 0.f};
#pragma unroll
    for (int m = 0; m < MR; m++)
#pragma unroll
        for (int n = 0; n < NR; n++) acc[m][n] = zero;

    stage(0, 0);

    const int nt = K / 64;
    int cur = 0;
    for (int t0 = 0; t0 < nt; t0++) {
        if (t0 + 1 < nt) { stage(cur ^ 1, (t0 + 1) * 64); waitcnt_vm<CHUNKS>(); }
        else             { waitcnt_vm<0>(); }
        __builtin_amdgcn_s_barrier();
        cfence();

#pragma unroll
        for (int kc = 0; kc < 2; kc++) {
            half8v af[MR], bf[NR];
#pragma unroll
            for (int m = 0; m < MR; m++) {
                int row = wr + m * 16 + r;
                af[m] = *(const half8v*)&As[cur][row * 64 + (((kc * 4 + g) ^ (r & 7)) * 8)];
            }
#pragma unroll
            for (int n = 0; n < NR; n++) {
                int row = wc + n * 16 + r;
                bf[n] = *(const half8v*)&Bs[cur][row * 64 + (((kc * 4 + g) ^ (r & 7)) * 8)];
            }
#pragma unroll
            for (int m = 0; m < MR; m++)
#pragma unroll
                for (int n = 0; n < NR; n++)
                    acc[m][n] = __builtin_amdgcn_mfma_f32_16x16x32_f16(af[m], bf[n], acc[m][n], 0, 0, 0);
        }
        cfence();
        __builtin_amdgcn_s_barrier();
        cur ^= 1;
    }

#pragma unroll
    for (int m = 0; m < MR; m++)
#pragma unroll
        for (int n = 0; n < NR; n++) {
            int col = row_b0 + wc + n * 16 + r;
            float bv = bias[col];
#pragma unroll
            for (int i = 0; i < 4; i++) {
                int row = row_a0 + wr + m * 16 + g * 4 + i;
                C[(size_t)row * N + col] = acc[m][n][i] + bv;
            }
        }
}

// ---------------- windowed attention + fused RoPE + proj_w cvt tail ----------------
__global__ __launch_bounds__(256) void attn_kernel(const _Float16* __restrict__ qkv,
                                                   const float* __restrict__ cosb,
                                                   const float* __restrict__ sinb,
                                                   _Float16* __restrict__ attn,
                                                   const float* __restrict__ projw,
                                                   _Float16* __restrict__ projw16)
{
    __shared__ _Float16 Qs[64][88], Ks[64][88], Vs[64][88];
    const int w = blockIdx.x, h = blockIdx.y;
    const int t = threadIdx.x, lane = t & 63, wave = t >> 6;
    const int g = lane >> 4, r = lane & 15;
    const int s0 = w * WIN;

#pragma unroll
    for (int i = 0; i < 5; i++) {
        int c = t + 256 * i;
        int row = c / 20, cc = (c % 20) * 4;
        int s = s0 + row;
        size_t base = (size_t)s * (3 * HID) + h * HD;
        int pc = (cc < 40) ? cc + 40 : cc - 40;
        float sign = (cc < 40) ? -1.f : 1.f;
        half4v q  = *(const half4v*)&qkv[base + cc];
        half4v qp = *(const half4v*)&qkv[base + pc];
        half4v k  = *(const half4v*)&qkv[base + HID + cc];
        half4v kp = *(const half4v*)&qkv[base + HID + pc];
        half4v v  = *(const half4v*)&qkv[base + 2 * HID + cc];
        float4v cs = *(const float4v*)&cosb[(size_t)s * HD + cc];
        float4v sn = *(const float4v*)&sinb[(size_t)s * HD + cc];
        half4v qo, ko;
#pragma unroll
        for (int j = 0; j < 4; j++) {
            qo[j] = (_Float16)((float)q[j] * cs[j] + sign * (float)qp[j] * sn[j]);
            ko[j] = (_Float16)((float)k[j] * cs[j] + sign * (float)kp[j] * sn[j]);
        }
        *(half4v*)&Qs[row][cc] = qo;
        *(half4v*)&Ks[row][cc] = ko;
        *(half4v*)&Vs[row][cc] = v;
    }
    __syncthreads();

    float4v sc[4];
    const float4v zero = {0.f, 0.f, 0.f, 0.f};
#pragma unroll
    for (int kt = 0; kt < 4; kt++) sc[kt] = zero;
#pragma unroll
    for (int hc = 0; hc < 5; hc++) {
        half4v qf = *(const half4v*)&Qs[wave * 16 + r][hc * 16 + g * 4];
#pragma unroll
        for (int kt = 0; kt < 4; kt++) {
            half4v kf = *(const half4v*)&Ks[kt * 16 + r][hc * 16 + g * 4];
            sc[kt] = __builtin_amdgcn_mfma_f32_16x16x16f16(kf, qf, sc[kt], 0, 0, 0);
        }
    }

    const float scale = 0.11180339887498948f;
    float mx = -1e30f;
#pragma unroll
    for (int kt = 0; kt < 4; kt++)
#pragma unroll
        for (int i = 0; i < 4; i++) { sc[kt][i] *= scale; mx = fmaxf(mx, sc[kt][i]); }
    mx = fmaxf(mx, __shfl_xor(mx, 16));
    mx = fmaxf(mx, __shfl_xor(mx, 32));
    float sum = 0.f;
#pragma unroll
    for (int kt = 0; kt < 4; kt++)
#pragma unroll
        for (int i = 0; i < 4; i++) { float e = __expf(sc[kt][i] - mx); sc[kt][i] = e; sum += e; }
    sum += __shfl_xor(sum, 16);
    sum += __shfl_xor(sum, 32);
    float inv = 1.f / sum;

    half4v pa[4];
#pragma unroll
    for (int kc = 0; kc < 4; kc++) {
        pa[kc][0] = (_Float16)(sc[kc][0] * inv);
        pa[kc][1] = (_Float16)(sc[kc][1] * inv);
        pa[kc][2] = (_Float16)(sc[kc][2] * inv);
        pa[kc][3] = (_Float16)(sc[kc][3] * inv);
    }

#pragma unroll
    for (int n = 0; n < 5; n++) {
        float4v o = zero;
#pragma unroll
        for (int kc = 0; kc < 4; kc++) {
            half4v vf;
#pragma unroll
            for (int j = 0; j < 4; j++) vf[j] = Vs[kc * 16 + g * 4 + j][n * 16 + r];
            o = __builtin_amdgcn_mfma_f32_16x16x16f16(pa[kc], vf, o, 0, 0, 0);
        }
#pragma unroll
        for (int i = 0; i < 4; i++) {
            int qrow = s0 + wave * 16 + g * 4 + i;
            attn[(size_t)qrow * HID + h * HD + n * 16 + r] = (_Float16)o[i];
        }
    }

    // proj_w fp32 -> fp16, hidden under attn (completes before proj via stream order)
    const int np4 = HID * HID / 4;
    const int bid = blockIdx.y * gridDim.x + blockIdx.x;
    const int stride = gridDim.x * gridDim.y * 256;
    for (int i = bid * 256 + t; i < np4; i += stride) {
        float4v v = ((const float4v*)projw)[i];
        half4v hh;
        hh[0] = (_Float16)v[0]; hh[1] = (_Float16)v[1];
        hh[2] = (_Float16)v[2]; hh[3] = (_Float16)v[3];
        ((half4v*)projw16)[i] = hh;
    }
}

// ---------------- launch ----------------
extern "C" void kernel_launch(void* const* d_in, const int* in_sizes, int n_in,
                              void* d_out, int out_size, void* d_ws, size_t ws_size,
                              hipStream_t stream)
{
    const float* hidden = (const float*)d_in[0];
    const float* cosb   = (const float*)d_in[1];
    const float* sinb   = (const float*)d_in[2];
    const float* qkv_w  = (const float*)d_in[3];
    const float* qkv_b  = (const float*)d_in[4];
    const float* proj_w = (const float*)d_in[5];
    const float* proj_b = (const float*)d_in[6];

    _Float16* hidden16 = (_Float16*)d_ws;                      // 2048*1280
    _Float16* qkvw16   = hidden16 + (size_t)S_LEN * HID;       // 3840*1280
    _Float16* projw16  = qkvw16 + (size_t)3 * HID * HID;       // 1280*1280
    _Float16* qkv16    = projw16 + (size_t)HID * HID;          // 2048*3840
    _Float16* attn16   = qkv16 + (size_t)S_LEN * 3 * HID;      // 2048*1280

    const int na4 = S_LEN * HID / 4, nb4 = 3 * HID * HID / 4;
    cvt_two<<<(na4 + nb4 + 255) / 256, 256, 0, stream>>>(
        hidden, hidden16, na4, qkv_w, qkvw16, nb4);

    // qkv: register-direct, 480 blocks x 256 thr (4 waves), no LDS/barriers
    gemm_qkv_reg<<<dim3(S_LEN / 128, 3 * HID / 128), 256, 0, stream>>>(
        hidden16, qkvw16, qkv_b, qkv16);

    attn_kernel<<<dim3(NWIN, NH), 256, 0, stream>>>(
        qkv16, cosb, sinb, attn16, proj_w, projw16);

    gemm_proj<<<dim3(S_LEN / 64, HID / 128), 512, 0, stream>>>(
        attn16, projw16, proj_b, (float*)d_out);
}

// Round 12
// 74.655 us; speedup vs baseline: 1.5234x; 1.5234x over previous
//
#include <hip/hip_runtime.h>

#define S_LEN 2048
#define HID   1280
#define NH    16
#define HD    80
#define WIN   64
#define NWIN  (S_LEN / WIN)

typedef _Float16 half4v __attribute__((ext_vector_type(4)));
typedef _Float16 half8v __attribute__((ext_vector_type(8)));
typedef float    float4v __attribute__((ext_vector_type(4)));

__device__ __forceinline__ void gload16(const _Float16* g, _Float16* l)
{
    __builtin_amdgcn_global_load_lds((const __attribute__((address_space(1))) void*)g,
                                     (__attribute__((address_space(3))) void*)l,
                                     16, 0, 0);
}

template <int N>
__device__ __forceinline__ void waitcnt_vm()
{
    if constexpr (N == 0)      asm volatile("s_waitcnt vmcnt(0)" ::: "memory");
    else if constexpr (N == 3) asm volatile("s_waitcnt vmcnt(3)" ::: "memory");
    else static_assert(N < 0, "add literal");
}

__device__ __forceinline__ void cfence() { asm volatile("" ::: "memory"); }

// ---------------- fp32 -> fp16 conversion (hidden + qkv_w) ----------------
__global__ void cvt_two(const float* __restrict__ a, _Float16* __restrict__ oa, int na4,
                        const float* __restrict__ b, _Float16* __restrict__ ob, int nb4)
{
    int i = blockIdx.x * blockDim.x + threadIdx.x;
    const float* in; _Float16* out; int idx;
    if (i < na4)            { in = a; out = oa; idx = i; }
    else if (i < na4 + nb4) { in = b; out = ob; idx = i - na4; }
    else return;
    float4v v = ((const float4v*)in)[idx];
    half4v h;
    h[0] = (_Float16)v[0]; h[1] = (_Float16)v[1];
    h[2] = (_Float16)v[2]; h[3] = (_Float16)v[3];
    ((half4v*)out)[idx] = h;
}

// ---------------- NT GEMM, 64x128 tile (the structure that measured ~670 TF) ----------------
// BK=64, 512 thr (8 waves 2x4, per-wave 32x32), double-buffered LDS (48 KB ->
// 3 blocks/CU = 24 waves/CU), gload_lds both operands with inverse-swizzled
// source (rule #21), counted vmcnt(3) prefetch (T4).
// Swizzle: phys col16 = logical col16 ^ (row & 7) -> conflict-free ds_read_b128.
template <typename OutT>
__global__ __launch_bounds__(512) void gemm_nt64(
    const _Float16* __restrict__ A,    // [M][K]
    const _Float16* __restrict__ B,    // [N][K]
    const float*    __restrict__ bias, // [N]
    OutT*           __restrict__ C,    // [M][N]
    int N, int K)
{
    constexpr int MR = 2, NR = 2, CA = 1, CB = 2, CHUNKS = 3;
    __shared__ _Float16 As[2][64 * 64];
    __shared__ _Float16 Bs[2][128 * 64];

    const int t = threadIdx.x;
    const int lane = t & 63, wave = t >> 6;
    const int g = lane >> 4, r = lane & 15;
    const int wr = (wave >> 2) * 32, wc = (wave & 3) * 32;
    const int row_a0 = blockIdx.x * 64, row_b0 = blockIdx.y * 128;

    const int srow = lane >> 3;
    const int scol = ((lane & 7) ^ srow) * 8;

    auto stage = [&](int buf, int k0) {
#pragma unroll
        for (int i = 0; i < CA; i++) {
            int c = wave * CA + i;
            gload16(&A[(size_t)(row_a0 + c * 8 + srow) * K + k0 + scol], &As[buf][c * 512]);
        }
#pragma unroll
        for (int i = 0; i < CB; i++) {
            int c = wave * CB + i;
            gload16(&B[(size_t)(row_b0 + c * 8 + srow) * K + k0 + scol], &Bs[buf][c * 512]);
        }
    };

    float4v acc[MR][NR];
    const float4v zero = {0.f, 0.f, 0.f, 0.f};
#pragma unroll
    for (int m = 0; m < MR; m++)
#pragma unroll
        for (int n = 0; n < NR; n++) acc[m][n] = zero;

    stage(0, 0);

    const int nt = K / 64;
    int cur = 0;
    for (int t0 = 0; t0 < nt; t0++) {
        if (t0 + 1 < nt) { stage(cur ^ 1, (t0 + 1) * 64); waitcnt_vm<CHUNKS>(); }
        else             { waitcnt_vm<0>(); }
        __builtin_amdgcn_s_barrier();
        cfence();

#pragma unroll
        for (int kc = 0; kc < 2; kc++) {
            half8v af[MR], bf[NR];
#pragma unroll
            for (int m = 0; m < MR; m++) {
                int row = wr + m * 16 + r;
                af[m] = *(const half8v*)&As[cur][row * 64 + (((kc * 4 + g) ^ (r & 7)) * 8)];
            }
#pragma unroll
            for (int n = 0; n < NR; n++) {
                int row = wc + n * 16 + r;
                bf[n] = *(const half8v*)&Bs[cur][row * 64 + (((kc * 4 + g) ^ (r & 7)) * 8)];
            }
#pragma unroll
            for (int m = 0; m < MR; m++)
#pragma unroll
                for (int n = 0; n < NR; n++)
                    acc[m][n] = __builtin_amdgcn_mfma_f32_16x16x32_f16(af[m], bf[n], acc[m][n], 0, 0, 0);
        }
        cfence();
        __builtin_amdgcn_s_barrier();
        cur ^= 1;
    }

#pragma unroll
    for (int m = 0; m < MR; m++)
#pragma unroll
        for (int n = 0; n < NR; n++) {
            int col = row_b0 + wc + n * 16 + r;
            float bv = bias[col];
#pragma unroll
            for (int i = 0; i < 4; i++) {
                int row = row_a0 + wr + m * 16 + g * 4 + i;
                C[(size_t)row * N + col] = (OutT)(acc[m][n][i] + bv);
            }
        }
}

// ---------------- windowed attention + fused RoPE + proj_w cvt tail ----------------
__global__ __launch_bounds__(256) void attn_kernel(const _Float16* __restrict__ qkv,
                                                   const float* __restrict__ cosb,
                                                   const float* __restrict__ sinb,
                                                   _Float16* __restrict__ attn,
                                                   const float* __restrict__ projw,
                                                   _Float16* __restrict__ projw16)
{
    __shared__ _Float16 Qs[64][88], Ks[64][88], Vs[64][88];
    const int w = blockIdx.x, h = blockIdx.y;
    const int t = threadIdx.x, lane = t & 63, wave = t >> 6;
    const int g = lane >> 4, r = lane & 15;
    const int s0 = w * WIN;

#pragma unroll
    for (int i = 0; i < 5; i++) {
        int c = t + 256 * i;
        int row = c / 20, cc = (c % 20) * 4;
        int s = s0 + row;
        size_t base = (size_t)s * (3 * HID) + h * HD;
        int pc = (cc < 40) ? cc + 40 : cc - 40;
        float sign = (cc < 40) ? -1.f : 1.f;
        half4v q  = *(const half4v*)&qkv[base + cc];
        half4v qp = *(const half4v*)&qkv[base + pc];
        half4v k  = *(const half4v*)&qkv[base + HID + cc];
        half4v kp = *(const half4v*)&qkv[base + HID + pc];
        half4v v  = *(const half4v*)&qkv[base + 2 * HID + cc];
        float4v cs = *(const float4v*)&cosb[(size_t)s * HD + cc];
        float4v sn = *(const float4v*)&sinb[(size_t)s * HD + cc];
        half4v qo, ko;
#pragma unroll
        for (int j = 0; j < 4; j++) {
            qo[j] = (_Float16)((float)q[j] * cs[j] + sign * (float)qp[j] * sn[j]);
            ko[j] = (_Float16)((float)k[j] * cs[j] + sign * (float)kp[j] * sn[j]);
        }
        *(half4v*)&Qs[row][cc] = qo;
        *(half4v*)&Ks[row][cc] = ko;
        *(half4v*)&Vs[row][cc] = v;
    }
    __syncthreads();

    float4v sc[4];
    const float4v zero = {0.f, 0.f, 0.f, 0.f};
#pragma unroll
    for (int kt = 0; kt < 4; kt++) sc[kt] = zero;
#pragma unroll
    for (int hc = 0; hc < 5; hc++) {
        half4v qf = *(const half4v*)&Qs[wave * 16 + r][hc * 16 + g * 4];
#pragma unroll
        for (int kt = 0; kt < 4; kt++) {
            half4v kf = *(const half4v*)&Ks[kt * 16 + r][hc * 16 + g * 4];
            sc[kt] = __builtin_amdgcn_mfma_f32_16x16x16f16(kf, qf, sc[kt], 0, 0, 0);
        }
    }

    const float scale = 0.11180339887498948f;
    float mx = -1e30f;
#pragma unroll
    for (int kt = 0; kt < 4; kt++)
#pragma unroll
        for (int i = 0; i < 4; i++) { sc[kt][i] *= scale; mx = fmaxf(mx, sc[kt][i]); }
    mx = fmaxf(mx, __shfl_xor(mx, 16));
    mx = fmaxf(mx, __shfl_xor(mx, 32));
    float sum = 0.f;
#pragma unroll
    for (int kt = 0; kt < 4; kt++)
#pragma unroll
        for (int i = 0; i < 4; i++) { float e = __expf(sc[kt][i] - mx); sc[kt][i] = e; sum += e; }
    sum += __shfl_xor(sum, 16);
    sum += __shfl_xor(sum, 32);
    float inv = 1.f / sum;

    half4v pa[4];
#pragma unroll
    for (int kc = 0; kc < 4; kc++) {
        pa[kc][0] = (_Float16)(sc[kc][0] * inv);
        pa[kc][1] = (_Float16)(sc[kc][1] * inv);
        pa[kc][2] = (_Float16)(sc[kc][2] * inv);
        pa[kc][3] = (_Float16)(sc[kc][3] * inv);
    }

#pragma unroll
    for (int n = 0; n < 5; n++) {
        float4v o = zero;
#pragma unroll
        for (int kc = 0; kc < 4; kc++) {
            half4v vf;
#pragma unroll
            for (int j = 0; j < 4; j++) vf[j] = Vs[kc * 16 + g * 4 + j][n * 16 + r];
            o = __builtin_amdgcn_mfma_f32_16x16x16f16(pa[kc], vf, o, 0, 0, 0);
        }
#pragma unroll
        for (int i = 0; i < 4; i++) {
            int qrow = s0 + wave * 16 + g * 4 + i;
            attn[(size_t)qrow * HID + h * HD + n * 16 + r] = (_Float16)o[i];
        }
    }

    // proj_w fp32 -> fp16, hidden under attn (completes before proj via stream order)
    const int np4 = HID * HID / 4;
    const int bid = blockIdx.y * gridDim.x + blockIdx.x;
    const int stride = gridDim.x * gridDim.y * 256;
    for (int i = bid * 256 + t; i < np4; i += stride) {
        float4v v = ((const float4v*)projw)[i];
        half4v hh;
        hh[0] = (_Float16)v[0]; hh[1] = (_Float16)v[1];
        hh[2] = (_Float16)v[2]; hh[3] = (_Float16)v[3];
        ((half4v*)projw16)[i] = hh;
    }
}

// ---------------- launch ----------------
extern "C" void kernel_launch(void* const* d_in, const int* in_sizes, int n_in,
                              void* d_out, int out_size, void* d_ws, size_t ws_size,
                              hipStream_t stream)
{
    const float* hidden = (const float*)d_in[0];
    const float* cosb   = (const float*)d_in[1];
    const float* sinb   = (const float*)d_in[2];
    const float* qkv_w  = (const float*)d_in[3];
    const float* qkv_b  = (const float*)d_in[4];
    const float* proj_w = (const float*)d_in[5];
    const float* proj_b = (const float*)d_in[6];

    _Float16* hidden16 = (_Float16*)d_ws;                      // 2048*1280
    _Float16* qkvw16   = hidden16 + (size_t)S_LEN * HID;       // 3840*1280
    _Float16* projw16  = qkvw16 + (size_t)3 * HID * HID;       // 1280*1280
    _Float16* qkv16    = projw16 + (size_t)HID * HID;          // 2048*3840
    _Float16* attn16   = qkv16 + (size_t)S_LEN * 3 * HID;      // 2048*1280

    const int na4 = S_LEN * HID / 4, nb4 = 3 * HID * HID / 4;
    cvt_two<<<(na4 + nb4 + 255) / 256, 256, 0, stream>>>(
        hidden, hidden16, na4, qkv_w, qkvw16, nb4);

    // qkv: 64x128 tiles -> (32, 30) = 960 blocks, 3 blocks/CU
    gemm_nt64<_Float16><<<dim3(S_LEN / 64, 3 * HID / 128), 512, 0, stream>>>(
        hidden16, qkvw16, qkv_b, qkv16, 3 * HID, HID);

    attn_kernel<<<dim3(NWIN, NH), 256, 0, stream>>>(
        qkv16, cosb, sinb, attn16, proj_w, projw16);

    // proj: 64x128 tiles -> (32, 10) = 320 blocks
    gemm_nt64<float><<<dim3(S_LEN / 64, HID / 128), 512, 0, stream>>>(
        attn16, projw16, proj_b, (float*)d_out, HID, HID);
}

// Round 13
// 66.859 us; speedup vs baseline: 1.7010x; 1.1166x over previous
//
#include <hip/hip_runtime.h>

#define S_LEN 2048
#define HID   1280
#define NH    16
#define HD    80
#define WIN   64
#define NWIN  (S_LEN / WIN)

typedef _Float16 half4v __attribute__((ext_vector_type(4)));
typedef _Float16 half8v __attribute__((ext_vector_type(8)));
typedef float    float4v __attribute__((ext_vector_type(4)));

__device__ __forceinline__ void gload16(const _Float16* g, _Float16* l)
{
    __builtin_amdgcn_global_load_lds((const __attribute__((address_space(1))) void*)g,
                                     (__attribute__((address_space(3))) void*)l,
                                     16, 0, 0);
}

template <int N>
__device__ __forceinline__ void waitcnt_vm()
{
    if constexpr (N == 0)      asm volatile("s_waitcnt vmcnt(0)" ::: "memory");
    else if constexpr (N == 3) asm volatile("s_waitcnt vmcnt(3)" ::: "memory");
    else if constexpr (N == 6) asm volatile("s_waitcnt vmcnt(6)" ::: "memory");
    else static_assert(N < 0, "add literal");
}

__device__ __forceinline__ void cfence() { asm volatile("" ::: "memory"); }

// ---------------- merged fp32 -> fp16 conversion (3 buffers, one launch) ----------------
__global__ void cvt_all(const float* __restrict__ a, _Float16* __restrict__ oa, int na4,
                        const float* __restrict__ b, _Float16* __restrict__ ob, int nb4,
                        const float* __restrict__ c, _Float16* __restrict__ oc, int nc4)
{
    int i = blockIdx.x * blockDim.x + threadIdx.x;
    const float* in; _Float16* out; int idx;
    if (i < na4)                  { in = a; out = oa; idx = i; }
    else if (i < na4 + nb4)       { in = b; out = ob; idx = i - na4; }
    else if (i < na4 + nb4 + nc4) { in = c; out = oc; idx = i - na4 - nb4; }
    else return;
    float4v v = ((const float4v*)in)[idx];
    half4v h;
    h[0] = (_Float16)v[0]; h[1] = (_Float16)v[1];
    h[2] = (_Float16)v[2]; h[3] = (_Float16)v[3];
    ((half4v*)out)[idx] = h;
}

// ---------------- qkv GEMM: 128x256 tile (traffic-minimizing) ----------------
// C[2048][3840] = A[2048][1280] * B[3840][1280]^T + bias.
// Grid: 240 blocks 1D (16x15 tiles), bijective XCD swizzle (240 = 8 x 30):
// XCD k gets 30 consecutive x-major tiles -> B-panels shared in its L2.
// BK=64, 512 thr (8 waves 2x4, per-wave 64x64 = 4x4 frags), dbuf LDS 96 KB,
// counted vmcnt(6) prefetch (T4), XOR-swizzled LDS via inverse-swz source.
__global__ __launch_bounds__(512) void gemm_qkv(
    const _Float16* __restrict__ A,    // [2048][1280]
    const _Float16* __restrict__ B,    // [3840][1280]
    const float*    __restrict__ bias,
    _Float16*       __restrict__ C)    // [2048][3840]
{
    constexpr int K = HID, N = 3 * HID, BK = 64;
    constexpr int MR = 4, NR = 4;
    constexpr int CA = 2, CB = 4, CHUNKS = 6;   // per-wave staging chunks
    __shared__ _Float16 As[2][128 * BK];        // 32 KB
    __shared__ _Float16 Bs[2][256 * BK];        // 64 KB

    const int t = threadIdx.x;
    const int lane = t & 63, wave = t >> 6;
    const int g = lane >> 4, r = lane & 15;
    const int wr = (wave >> 2) * 64, wc = (wave & 3) * 64;

    // XCD swizzle: bid%8 = XCD (dispatch round-robin) -> give it 30 contiguous tiles
    const int tile = (blockIdx.x % 8) * 30 + (blockIdx.x / 8);
    const int row_a0 = (tile % 16) * 128;
    const int row_b0 = (tile / 16) * 256;

    const int srow = lane >> 3;
    const int scol = ((lane & 7) ^ srow) * 8;   // inverse-swizzled global col

    auto stage = [&](int buf, int k0) {
#pragma unroll
        for (int i = 0; i < CA; i++) {
            int c = wave * CA + i;              // A chunks 0..15
            gload16(&A[(size_t)(row_a0 + c * 8 + srow) * K + k0 + scol], &As[buf][c * 512]);
        }
#pragma unroll
        for (int i = 0; i < CB; i++) {
            int c = wave * CB + i;              // B chunks 0..31
            gload16(&B[(size_t)(row_b0 + c * 8 + srow) * K + k0 + scol], &Bs[buf][c * 512]);
        }
    };

    float4v acc[MR][NR];
    const float4v zero = {0.f, 0.f, 0.f, 0.f};
#pragma unroll
    for (int m = 0; m < MR; m++)
#pragma unroll
        for (int n = 0; n < NR; n++) acc[m][n] = zero;

    stage(0, 0);

    const int nt = K / BK;                       // 20
    int cur = 0;
    for (int t0 = 0; t0 < nt; t0++) {
        if (t0 + 1 < nt) { stage(cur ^ 1, (t0 + 1) * BK); waitcnt_vm<CHUNKS>(); }
        else             { waitcnt_vm<0>(); }
        __builtin_amdgcn_s_barrier();
        cfence();

#pragma unroll
        for (int kc = 0; kc < 2; kc++) {
            half8v af[MR], bf[NR];
#pragma unroll
            for (int m = 0; m < MR; m++) {
                int row = wr + m * 16 + r;
                af[m] = *(const half8v*)&As[cur][row * 64 + (((kc * 4 + g) ^ (r & 7)) * 8)];
            }
#pragma unroll
            for (int n = 0; n < NR; n++) {
                int row = wc + n * 16 + r;
                bf[n] = *(const half8v*)&Bs[cur][row * 64 + (((kc * 4 + g) ^ (r & 7)) * 8)];
            }
#pragma unroll
            for (int m = 0; m < MR; m++)
#pragma unroll
                for (int n = 0; n < NR; n++)
                    acc[m][n] = __builtin_amdgcn_mfma_f32_16x16x32_f16(af[m], bf[n], acc[m][n], 0, 0, 0);
        }
        cfence();
        __builtin_amdgcn_s_barrier();
        cur ^= 1;
    }

#pragma unroll
    for (int m = 0; m < MR; m++)
#pragma unroll
        for (int n = 0; n < NR; n++) {
            int col = row_b0 + wc + n * 16 + r;
            float bv = bias[col];
#pragma unroll
            for (int i = 0; i < 4; i++) {
                int row = row_a0 + wr + m * 16 + g * 4 + i;
                C[(size_t)row * N + col] = (_Float16)(acc[m][n][i] + bv);
            }
        }
}

// ---------------- proj GEMM: 64x128 tile (r5-verified structure) ----------------
__global__ __launch_bounds__(512) void gemm_proj(
    const _Float16* __restrict__ A,    // attn16 [2048][1280]
    const _Float16* __restrict__ B,    // projw16 [1280][1280]
    const float*    __restrict__ bias,
    float*          __restrict__ C)    // [2048][1280]
{
    constexpr int K = HID, N = HID;
    constexpr int MR = 2, NR = 2, CA = 1, CB = 2, CHUNKS = 3;
    __shared__ _Float16 As[2][64 * 64];
    __shared__ _Float16 Bs[2][128 * 64];

    const int t = threadIdx.x;
    const int lane = t & 63, wave = t >> 6;
    const int g = lane >> 4, r = lane & 15;
    const int wr = (wave >> 2) * 32, wc = (wave & 3) * 32;
    const int row_a0 = blockIdx.x * 64, row_b0 = blockIdx.y * 128;

    const int srow = lane >> 3;
    const int scol = ((lane & 7) ^ srow) * 8;

    auto stage = [&](int buf, int k0) {
#pragma unroll
        for (int i = 0; i < CA; i++) {
            int c = wave * CA + i;
            gload16(&A[(size_t)(row_a0 + c * 8 + srow) * K + k0 + scol], &As[buf][c * 512]);
        }
#pragma unroll
        for (int i = 0; i < CB; i++) {
            int c = wave * CB + i;
            gload16(&B[(size_t)(row_b0 + c * 8 + srow) * K + k0 + scol], &Bs[buf][c * 512]);
        }
    };

    float4v acc[MR][NR];
    const float4v zero = {0.f, 0.f, 0.f, 0.f};
#pragma unroll
    for (int m = 0; m < MR; m++)
#pragma unroll
        for (int n = 0; n < NR; n++) acc[m][n] = zero;

    stage(0, 0);

    const int nt = K / 64;
    int cur = 0;
    for (int t0 = 0; t0 < nt; t0++) {
        if (t0 + 1 < nt) { stage(cur ^ 1, (t0 + 1) * 64); waitcnt_vm<CHUNKS>(); }
        else             { waitcnt_vm<0>(); }
        __builtin_amdgcn_s_barrier();
        cfence();

#pragma unroll
        for (int kc = 0; kc < 2; kc++) {
            half8v af[MR], bf[NR];
#pragma unroll
            for (int m = 0; m < MR; m++) {
                int row = wr + m * 16 + r;
                af[m] = *(const half8v*)&As[cur][row * 64 + (((kc * 4 + g) ^ (r & 7)) * 8)];
            }
#pragma unroll
            for (int n = 0; n < NR; n++) {
                int row = wc + n * 16 + r;
                bf[n] = *(const half8v*)&Bs[cur][row * 64 + (((kc * 4 + g) ^ (r & 7)) * 8)];
            }
#pragma unroll
            for (int m = 0; m < MR; m++)
#pragma unroll
                for (int n = 0; n < NR; n++)
                    acc[m][n] = __builtin_amdgcn_mfma_f32_16x16x32_f16(af[m], bf[n], acc[m][n], 0, 0, 0);
        }
        cfence();
        __builtin_amdgcn_s_barrier();
        cur ^= 1;
    }

#pragma unroll
    for (int m = 0; m < MR; m++)
#pragma unroll
        for (int n = 0; n < NR; n++) {
            int col = row_b0 + wc + n * 16 + r;
            float bv = bias[col];
#pragma unroll
            for (int i = 0; i < 4; i++) {
                int row = row_a0 + wr + m * 16 + g * 4 + i;
                C[(size_t)row * N + col] = acc[m][n][i] + bv;
            }
        }
}

// ---------------- windowed attention with fused RoPE (r5-verified) ----------------
__global__ __launch_bounds__(256) void attn_kernel(const _Float16* __restrict__ qkv,
                                                   const float* __restrict__ cosb,
                                                   const float* __restrict__ sinb,
                                                   _Float16* __restrict__ attn)
{
    __shared__ _Float16 Qs[64][88], Ks[64][88], Vs[64][88];
    const int w = blockIdx.x, h = blockIdx.y;
    const int t = threadIdx.x, lane = t & 63, wave = t >> 6;
    const int g = lane >> 4, r = lane & 15;
    const int s0 = w * WIN;

#pragma unroll
    for (int i = 0; i < 5; i++) {
        int c = t + 256 * i;
        int row = c / 20, cc = (c % 20) * 4;
        int s = s0 + row;
        size_t base = (size_t)s * (3 * HID) + h * HD;
        int pc = (cc < 40) ? cc + 40 : cc - 40;
        float sign = (cc < 40) ? -1.f : 1.f;
        half4v q  = *(const half4v*)&qkv[base + cc];
        half4v qp = *(const half4v*)&qkv[base + pc];
        half4v k  = *(const half4v*)&qkv[base + HID + cc];
        half4v kp = *(const half4v*)&qkv[base + HID + pc];
        half4v v  = *(const half4v*)&qkv[base + 2 * HID + cc];
        float4v cs = *(const float4v*)&cosb[(size_t)s * HD + cc];
        float4v sn = *(const float4v*)&sinb[(size_t)s * HD + cc];
        half4v qo, ko;
#pragma unroll
        for (int j = 0; j < 4; j++) {
            qo[j] = (_Float16)((float)q[j] * cs[j] + sign * (float)qp[j] * sn[j]);
            ko[j] = (_Float16)((float)k[j] * cs[j] + sign * (float)kp[j] * sn[j]);
        }
        *(half4v*)&Qs[row][cc] = qo;
        *(half4v*)&Ks[row][cc] = ko;
        *(half4v*)&Vs[row][cc] = v;
    }
    __syncthreads();

    float4v sc[4];
    const float4v zero = {0.f, 0.f, 0.f, 0.f};
#pragma unroll
    for (int kt = 0; kt < 4; kt++) sc[kt] = zero;
#pragma unroll
    for (int hc = 0; hc < 5; hc++) {
        half4v qf = *(const half4v*)&Qs[wave * 16 + r][hc * 16 + g * 4];
#pragma unroll
        for (int kt = 0; kt < 4; kt++) {
            half4v kf = *(const half4v*)&Ks[kt * 16 + r][hc * 16 + g * 4];
            sc[kt] = __builtin_amdgcn_mfma_f32_16x16x16f16(kf, qf, sc[kt], 0, 0, 0);
        }
    }

    const float scale = 0.11180339887498948f;
    float mx = -1e30f;
#pragma unroll
    for (int kt = 0; kt < 4; kt++)
#pragma unroll
        for (int i = 0; i < 4; i++) { sc[kt][i] *= scale; mx = fmaxf(mx, sc[kt][i]); }
    mx = fmaxf(mx, __shfl_xor(mx, 16));
    mx = fmaxf(mx, __shfl_xor(mx, 32));
    float sum = 0.f;
#pragma unroll
    for (int kt = 0; kt < 4; kt++)
#pragma unroll
        for (int i = 0; i < 4; i++) { float e = __expf(sc[kt][i] - mx); sc[kt][i] = e; sum += e; }
    sum += __shfl_xor(sum, 16);
    sum += __shfl_xor(sum, 32);
    float inv = 1.f / sum;

    half4v pa[4];
#pragma unroll
    for (int kc = 0; kc < 4; kc++) {
        pa[kc][0] = (_Float16)(sc[kc][0] * inv);
        pa[kc][1] = (_Float16)(sc[kc][1] * inv);
        pa[kc][2] = (_Float16)(sc[kc][2] * inv);
        pa[kc][3] = (_Float16)(sc[kc][3] * inv);
    }

#pragma unroll
    for (int n = 0; n < 5; n++) {
        float4v o = zero;
#pragma unroll
        for (int kc = 0; kc < 4; kc++) {
            half4v vf;
#pragma unroll
            for (int j = 0; j < 4; j++) vf[j] = Vs[kc * 16 + g * 4 + j][n * 16 + r];
            o = __builtin_amdgcn_mfma_f32_16x16x16f16(pa[kc], vf, o, 0, 0, 0);
        }
#pragma unroll
        for (int i = 0; i < 4; i++) {
            int qrow = s0 + wave * 16 + g * 4 + i;
            attn[(size_t)qrow * HID + h * HD + n * 16 + r] = (_Float16)o[i];
        }
    }
}

// ---------------- launch ----------------
extern "C" void kernel_launch(void* const* d_in, const int* in_sizes, int n_in,
                              void* d_out, int out_size, void* d_ws, size_t ws_size,
                              hipStream_t stream)
{
    const float* hidden = (const float*)d_in[0];
    const float* cosb   = (const float*)d_in[1];
    const float* sinb   = (const float*)d_in[2];
    const float* qkv_w  = (const float*)d_in[3];
    const float* qkv_b  = (const float*)d_in[4];
    const float* proj_w = (const float*)d_in[5];
    const float* proj_b = (const float*)d_in[6];

    _Float16* hidden16 = (_Float16*)d_ws;                      // 2048*1280
    _Float16* qkvw16   = hidden16 + (size_t)S_LEN * HID;       // 3840*1280
    _Float16* projw16  = qkvw16 + (size_t)3 * HID * HID;       // 1280*1280
    _Float16* qkv16    = projw16 + (size_t)HID * HID;          // 2048*3840
    _Float16* attn16   = qkv16 + (size_t)S_LEN * 3 * HID;      // 2048*1280

    const int na4 = S_LEN * HID / 4, nb4 = 3 * HID * HID / 4, nc4 = HID * HID / 4;
    cvt_all<<<(na4 + nb4 + nc4 + 255) / 256, 256, 0, stream>>>(
        hidden, hidden16, na4, qkv_w, qkvw16, nb4, proj_w, projw16, nc4);

    // qkv: 128x256 tiles -> 240 blocks 1D, XCD-swizzled
    gemm_qkv<<<240, 512, 0, stream>>>(hidden16, qkvw16, qkv_b, qkv16);

    attn_kernel<<<dim3(NWIN, NH), 256, 0, stream>>>(qkv16, cosb, sinb, attn16);

    // proj: 64x128 tiles -> 320 blocks
    gemm_proj<<<dim3(S_LEN / 64, HID / 128), 512, 0, stream>>>(
        attn16, projw16, proj_b, (float*)d_out);
}